// Round 11
// baseline (201.796 us; speedup 1.0000x reference)
//
#include <hip/hip_runtime.h>

// MixSelfAttention (B=2, L=1024, H=8, E=64), float32 in/out. 4 dispatches:
//   D1 d1: k1 circular-corr, FULL t-range per (bh,eg) block (512 thr = 2 t-halves),
//          in-block half-combine + square + e-sum -> amp2part[bh][eg][tau] (1 MB)
//          (blocks 0..255) | kw tile-transpose W -> Wt[2048][1024] (256..767)
//   D2 d2: 32 blocks x 1024 thr; t: sum amp2part over eg + top35 -> St
//          tf: row norms + top35 -> Stf (single-wave selection)
//   D3 d3: kb direct-Wt WVp partials (0..1151) | k4 scores+softmax -> P (1152..1663)
//   D4 k6: per-bh blocks; Wv=sum_mc WVp staged in LDS + transposed P chunk

#define NTOP 35
#define NJ 70
#define LLMIN (-0x7FFFFFFFFFFFFFFFLL - 1)

static __device__ __forceinline__ void fma4(float4& a, float4 q, float4 k) {
  a.x = fmaf(q.x,k.x,a.x); a.y = fmaf(q.y,k.y,a.y);
  a.z = fmaf(q.z,k.z,a.z); a.w = fmaf(q.w,k.w,a.w);
}

// single-wave top-35 (threadIdx.x<64 calls), vals[1024] ready, jax tie-break
static __device__ __forceinline__ void wave_top35(const float* vals, int* out) {
  int lane = threadIdx.x;
  long long kreg[16];
  long long lmax = LLMIN;
  #pragma unroll
  for (int s = 0; s < 16; ++s) {
    int l = (s << 6) + lane;
    long long key = ((long long)(int)__float_as_uint(vals[l]) << 32)
                    | (unsigned int)(1023 - l);
    kreg[s] = key;
    lmax = key > lmax ? key : lmax;
  }
  for (int it = 0; it < NTOP; ++it) {
    long long g = lmax;
    #pragma unroll
    for (int off = 1; off < 64; off <<= 1) {
      long long o = __shfl_xor(g, off);
      g = o > g ? o : g;
    }
    if (lane == 0) out[it] = 1023 - (int)(g & 0xFFFFFFFFLL);
    if (lmax == g) {
      lmax = LLMIN;
      #pragma unroll
      for (int s = 0; s < 16; ++s) {
        if (kreg[s] == g) kreg[s] = LLMIN;
        lmax = kreg[s] > lmax ? kreg[s] : lmax;
      }
    }
  }
}

// ---------------- D1: k1 full-t (256 blocks) | kw (512 blocks), 512 thr ----------------
__global__ __launch_bounds__(512) void d1_prep(
    const float* __restrict__ q, const float* __restrict__ k,
    const float* __restrict__ w,
    float* __restrict__ Wt, float* __restrict__ amp2part) {
  __shared__ float smem[8192];          // 32 KB
  int bid = blockIdx.x;
  int tid = threadIdx.x;
  if (bid < 256) {                      // ---- k1: (bh, eg), full t ----
    int bh = bid & 15;  int eg = bid >> 4;
    int b = bh >> 3, h = bh & 7;
    float4* QP = reinterpret_cast<float4*>(smem);        // 8-plane swizzle
    float4* Ks = QP + 1024;
    const float* qb  = q + (size_t)b*524288 + h*64 + eg*4;
    const float* kbp = k + (size_t)b*524288 + h*64 + eg*4;
    for (int r = tid; r < 1024; r += 512)
      QP[(r & 7)*128 + (r >> 3)] =
          *reinterpret_cast<const float4*>(qb + (size_t)r*512);
    for (int i = tid; i < 1024; i += 512)
      Ks[i] = *reinterpret_cast<const float4*>(kbp + (size_t)i*512);
    __syncthreads();
    int half = tid >> 8, tg = tid & 255;
    int tb = tg << 2;                   // 4 taus per thread: tb..tb+3
    int tstart = half << 9;             // t in [tstart, tstart+512)
    float4 acc[4], wnd[4];
    #pragma unroll
    for (int i = 0; i < 4; ++i) {
      acc[i] = make_float4(0,0,0,0);
      int r = (tstart + tb + i) & 1023;
      wnd[i] = QP[(r & 7)*128 + (r >> 3)];
    }
    for (int t8 = 0; t8 < 512; t8 += 8) {
      #pragma unroll
      for (int s = 0; s < 8; ++s) {
        float4 kv = Ks[tstart + t8 + s];
        #pragma unroll
        for (int i = 0; i < 4; ++i)
          fma4(acc[i], wnd[(s + i) & 3], kv);   // acc FIXED per tau; Q row for
                                                // tau tb+i sits in slot (t+i)&3
        int rn = (tstart + t8 + s + tb + 4) & 1023;
        wnd[s & 3] = QP[(rn & 7)*128 + (rn >> 3)];   // overwrite slot t&3 with
                                                     // row t+tb+4 (needed at
                                                     // t+1 for i=3)
      }
    }
    __syncthreads();                    // QP/Ks dead; reuse smem for exchange
    if (half == 1) {
      float* rp = smem + tg*17;
      const float* a = reinterpret_cast<const float*>(acc);
      #pragma unroll
      for (int i = 0; i < 16; ++i) rp[i] = a[i];
    }
    __syncthreads();
    if (half == 0) {
      const float* rp = smem + tg*17;
      float* a = reinterpret_cast<float*>(acc);
      #pragma unroll
      for (int i = 0; i < 16; ++i) a[i] += rp[i];
      float4 r;
      r.x = acc[0].x*acc[0].x + acc[0].y*acc[0].y + acc[0].z*acc[0].z + acc[0].w*acc[0].w;
      r.y = acc[1].x*acc[1].x + acc[1].y*acc[1].y + acc[1].z*acc[1].z + acc[1].w*acc[1].w;
      r.z = acc[2].x*acc[2].x + acc[2].y*acc[2].y + acc[2].z*acc[2].z + acc[2].w*acc[2].w;
      r.w = acc[3].x*acc[3].x + acc[3].y*acc[3].y + acc[3].z*acc[3].z + acc[3].w*acc[3].w;
      *reinterpret_cast<float4*>(amp2part + (((size_t)(bh*16 + eg)) << 10) + tb) = r;
    }
  } else {                              // ---- kw ----
    int wid = bid - 256;
    int c0 = (wid & 31) << 6, r0 = (wid >> 5) << 6;
    float* tile = smem;                 // 64*65 floats
    #pragma unroll
    for (int s = 0; s < 8; ++s) {
      int idx = tid + (s << 9);
      int r = idx >> 6, c = idx & 63;
      tile[r*65 + c] = w[(size_t)(r0 + r)*2048 + c0 + c];
    }
    __syncthreads();
    #pragma unroll
    for (int s = 0; s < 8; ++s) {
      int idx = tid + (s << 9);
      int c = idx >> 6, r = idx & 63;
      Wt[(size_t)(c0 + c)*1024 + r0 + r] = tile[r*65 + c];
    }
  }
}

// ---------------- D2: top-35 both branches, 1024 threads ----------------
__global__ __launch_bounds__(1024) void d2_topk(
    const float* __restrict__ amp2part, const float* __restrict__ tfq,
    int* __restrict__ St, int* __restrict__ Stf) {
  __shared__ float vals[1024];
  int bid = blockIdx.x;
  int tid = threadIdx.x;
  bool isT = bid < 16;
  int bh = isT ? bid : bid - 16;
  if (isT) {                            // sum amp2part over eg (coalesced)
    float s = 0.f;
    #pragma unroll
    for (int eg = 0; eg < 16; ++eg)
      s += amp2part[(((size_t)(bh*16 + eg)) << 10) + tid];
    vals[tid] = s;
  } else {                              // tf row norms
    int b = bh >> 3, h = bh & 7;
    const float4* p = reinterpret_cast<const float4*>(
        tfq + (((size_t)(b*1024 + tid)*8 + h) << 6));
    float s = 0.f;
    #pragma unroll
    for (int i = 0; i < 16; ++i) {
      float4 vv = p[i];
      s += vv.x*vv.x + vv.y*vv.y + vv.z*vv.z + vv.w*vv.w;
    }
    vals[tid] = s;
  }
  __syncthreads();
  if (tid < 64) wave_top35(vals, (isT ? St : Stf) + bh*40);
}

// ---------------- D3: kb (direct Wt) | k4 ----------------
__global__ __launch_bounds__(256) void d3_mix(
    const float* __restrict__ q, const float* __restrict__ k,
    const float* __restrict__ tfq,
    const float* __restrict__ Wt, const float* __restrict__ bias,
    const float* __restrict__ values,
    const int* __restrict__ St, const int* __restrict__ Stf,
    float* __restrict__ WVp, float* __restrict__ P) {
  __shared__ float4 smbuf[1712];        // 27392 B (k4); kb uses first 4 KB
  float* f = reinterpret_cast<float*>(smbuf);
  int bid = blockIdx.x;
  int tid = threadIdx.x;
  if (bid < 1152) {                     // ---- kb: WVp partial, direct Wt ----
    int jq = bid / 64;                  // 0..17
    int rem = bid - jq*64;
    int bh = rem >> 2, mc = rem & 3;
    int b = bh >> 3, h = bh & 7;
    int j0 = jq << 2;
    const float* pj[4];
    #pragma unroll
    for (int x = 0; x < 4; ++x) {
      int j = j0 + x;
      if (j < NTOP)      pj[x] = Wt + (size_t)St [bh*40 + j]*1024;
      else if (j < NJ)   pj[x] = Wt + (size_t)(1024 + Stf[bh*40 + j-NTOP])*1024;
      else if (j == NJ)  pj[x] = bias;
      else               pj[x] = Wt;    // j==71: garbage, zeroed in epilogue
    }
    int d = tid & 63, mp = tid >> 6;
    int m0 = (mc << 8) + mp;
    float a0=0.f, a1=0.f, a2=0.f, a3=0.f;
    #pragma unroll 16
    for (int i = 0; i < 64; ++i) {
      int m = m0 + (i << 2);
      float vv = values[(((size_t)(b*1024 + m)*8 + h) << 6) + d];
      a0 = fmaf(pj[0][m], vv, a0);
      a1 = fmaf(pj[1][m], vv, a1);
      a2 = fmaf(pj[2][m], vv, a2);
      a3 = fmaf(pj[3][m], vv, a3);
    }
    float4* red = smbuf;
    red[tid] = make_float4(a0, a1, a2, a3);
    __syncthreads();
    int jj = tid >> 6, dd = tid & 63;
    float4 r0 = red[dd], r1 = red[64+dd], r2 = red[128+dd], r3 = red[192+dd];
    float s;
    if (jj == 0)      s = r0.x + r1.x + r2.x + r3.x;
    else if (jj == 1) s = r0.y + r1.y + r2.y + r3.y;
    else if (jj == 2) s = r0.z + r1.z + r2.z + r3.z;
    else              s = r0.w + r1.w + r2.w + r3.w;
    if (j0 + jj > NJ) s = 0.f;
    WVp[(size_t)mc*73728 + ((size_t)bh*72 + j0 + jj)*64 + dd] = s;
  } else {                              // ---- k4 ----
    int gid = bid - 1152;
    int bh = gid >> 5;  int m0 = (gid & 31) << 5;
    int b = bh >> 3, h = bh & 7;
    float* qs   = f;                    // 35*64
    float* ts   = f + 2240;
    float* sc   = f + 4480;             // 32*73
    float* invs = f + 6816;             // 32
    for (int i = tid; i < NTOP*64; i += 256) {
      int j = i >> 6, e = i & 63;
      qs[i] = q  [(((size_t)(b*1024 + St [bh*40 + j])*8 + h) << 6) + e];
      ts[i] = tfq[(((size_t)(b*1024 + Stf[bh*40 + j])*8 + h) << 6) + e];
    }
    __syncthreads();
    int mi = tid & 31, g = tid >> 5;
    int br = g >> 2, g4 = g & 3;
    int m = m0 + mi;
    const float* src = br ? tfq : k;
    float4 kr[16];
    const float4* p = reinterpret_cast<const float4*>(
        src + (((size_t)(b*1024 + m)*8 + h) << 6));
    #pragma unroll
    for (int i = 0; i < 16; ++i) kr[i] = p[i];
    const float4* fs4 = reinterpret_cast<const float4*>(br ? ts : qs);
    int sb = br ? NTOP : 0;
    for (int j = g4; j < NTOP; j += 4) {
      float s = 0.f;
      #pragma unroll
      for (int e4 = 0; e4 < 16; ++e4) {
        float4 qv = fs4[j*16 + e4];
        s += qv.x*kr[e4].x + qv.y*kr[e4].y + qv.z*kr[e4].z + qv.w*kr[e4].w;
      }
      sc[mi*73 + sb + j] = s * 0.125f;
    }
    __syncthreads();
    if (tid < 32) {
      float mx = -1e30f;
      for (int j = 0; j < NJ; ++j) mx = fmaxf(mx, sc[tid*73 + j]);
      float sum = 0.f;
      for (int j = 0; j < NJ; ++j) {
        float e = __expf(sc[tid*73 + j] - mx);
        sc[tid*73 + j] = e; sum += e;
      }
      invs[tid] = 1.0f / sum;
    }
    __syncthreads();
    float* Pb = P + ((size_t)bh*1024 + m0)*72;
    for (int i = tid; i < 32*72; i += 256) {
      int mm = i / 72, j = i - mm*72;
      Pb[i] = (j < NJ) ? sc[mm*73 + j] * invs[mm] : 0.f;
    }
  }
}

// ---------------- D4: k6 per-bh, LDS Wv + transposed P chunk ----------------
__global__ __launch_bounds__(256) void k6_out(
    const float* __restrict__ P, const float* __restrict__ WVp,
    float* __restrict__ out) {
  __shared__ float wv[72*64];           // 18432 B
  __shared__ float Pl[72*68];           // 19584 B
  int bh = blockIdx.x, lc = blockIdx.y;
  int l0 = lc << 6;
  int b = bh >> 3, h = bh & 7;
  int tid = threadIdx.x;
  {
    const float* W0 = WVp + (size_t)bh*4608;
    for (int i = tid; i < 4608; i += 256)
      wv[i] = W0[i] + W0[73728 + i] + W0[147456 + i] + W0[221184 + i];
  }
  {
    const float* Pg = P + ((size_t)bh*1024 + l0)*72;
    for (int i = tid; i < 4608; i += 256) {
      int l = i / 72, j = i - l*72;
      Pl[j*68 + l] = Pg[i];
    }
  }
  __syncthreads();
  int d = tid & 63, lg = tid >> 6;
  int lb = lg << 4;
  float acc[16];
  float base = wv[NJ*64 + d];
  #pragma unroll
  for (int i = 0; i < 16; ++i) acc[i] = base;
  for (int j = 0; j < NJ; ++j) {
    float wvj = wv[j*64 + d];
    const float4* pr = reinterpret_cast<const float4*>(Pl + j*68 + lb);
    float4 p0 = pr[0], p1 = pr[1], p2 = pr[2], p3 = pr[3];
    acc[0]  = fmaf(p0.x, wvj, acc[0]);  acc[1]  = fmaf(p0.y, wvj, acc[1]);
    acc[2]  = fmaf(p0.z, wvj, acc[2]);  acc[3]  = fmaf(p0.w, wvj, acc[3]);
    acc[4]  = fmaf(p1.x, wvj, acc[4]);  acc[5]  = fmaf(p1.y, wvj, acc[5]);
    acc[6]  = fmaf(p1.z, wvj, acc[6]);  acc[7]  = fmaf(p1.w, wvj, acc[7]);
    acc[8]  = fmaf(p2.x, wvj, acc[8]);  acc[9]  = fmaf(p2.y, wvj, acc[9]);
    acc[10] = fmaf(p2.z, wvj, acc[10]); acc[11] = fmaf(p2.w, wvj, acc[11]);
    acc[12] = fmaf(p3.x, wvj, acc[12]); acc[13] = fmaf(p3.y, wvj, acc[13]);
    acc[14] = fmaf(p3.z, wvj, acc[14]); acc[15] = fmaf(p3.w, wvj, acc[15]);
  }
  #pragma unroll
  for (int i = 0; i < 16; ++i) {
    int l = l0 + lb + i;
    out[(((size_t)(b*1024 + l)*8 + h) << 6) + d] = acc[i];
  }
}

extern "C" void kernel_launch(void* const* d_in, const int* in_sizes, int n_in,
                              void* d_out, int out_size, void* d_ws, size_t ws_size,
                              hipStream_t stream) {
  const float* tfq  = (const float*)d_in[0];
  const float* q    = (const float*)d_in[1];
  const float* k    = (const float*)d_in[2];
  const float* v    = (const float*)d_in[3];
  const float* tw   = (const float*)d_in[5];
  const float* tb   = (const float*)d_in[6];
  float* out = (float*)d_out;

  char* ws = (char*)d_ws;
  float* amp2part = (float*)(ws);                   // 1,048,576
  int*   St  = (int*)  (ws + 1048576);              // 4 KB
  int*   Stf = (int*)  (ws + 1052672);              // 4 KB
  float* Wt  = (float*)(ws + 1056768);              // 8,388,608
  float* P   = (float*)(ws + 9445376);              // 4,718,592
  float* WVp = (float*)(ws + 14163968);             // 1,179,648

  d1_prep<<<768, 512, 0, stream>>>(q, k, tw, Wt, amp2part);
  d2_topk<<<32, 1024, 0, stream>>>(amp2part, tfq, St, Stf);
  d3_mix <<<1664, 256, 0, stream>>>(q, k, tfq, Wt, tb, v, St, Stf, WVp, P);
  k6_out <<<dim3(16, 16), 256, 0, stream>>>(P, WVp, out);
}

// Round 12
// 185.456 us; speedup vs baseline: 1.0881x; 1.0881x over previous
//
#include <hip/hip_runtime.h>

// MixSelfAttention (B=2, L=1024, H=8, E=64), float32 in/out. 4 dispatches:
//   D1 d1: k1 circular-corr per (bh,eg) block, 512 thr = 4 t-chunks x 128 tau-grp
//          (8 taus/thread, XOR-swizzled LDS, in-block chunk combine) ->
//          amp2part[bh][eg][tau] (1 MB)  (blocks 0..255)
//          | kw tile-transpose W -> Wt[2048][1024] (blocks 256..767)
//   D2 d2: 32 blocks x 1024 thr; t: sum amp2part over eg + top35 -> St
//          tf: row norms + top35 -> Stf (single-wave selection)
//   D3 d3: kb direct-Wt WVp partials (0..1151) | k4 scores+softmax -> P (1152..1663)
//   D4 k6: per-bh blocks; Wv=sum_mc WVp staged in LDS + transposed P chunk

#define NTOP 35
#define NJ 70
#define LLMIN (-0x7FFFFFFFFFFFFFFFLL - 1)

static __device__ __forceinline__ void fma4(float4& a, float4 q, float4 k) {
  a.x = fmaf(q.x,k.x,a.x); a.y = fmaf(q.y,k.y,a.y);
  a.z = fmaf(q.z,k.z,a.z); a.w = fmaf(q.w,k.w,a.w);
}

// single-wave top-35 (threadIdx.x<64 calls), vals[1024] ready, jax tie-break
static __device__ __forceinline__ void wave_top35(const float* vals, int* out) {
  int lane = threadIdx.x;
  long long kreg[16];
  long long lmax = LLMIN;
  #pragma unroll
  for (int s = 0; s < 16; ++s) {
    int l = (s << 6) + lane;
    long long key = ((long long)(int)__float_as_uint(vals[l]) << 32)
                    | (unsigned int)(1023 - l);
    kreg[s] = key;
    lmax = key > lmax ? key : lmax;
  }
  for (int it = 0; it < NTOP; ++it) {
    long long g = lmax;
    #pragma unroll
    for (int off = 1; off < 64; off <<= 1) {
      long long o = __shfl_xor(g, off);
      g = o > g ? o : g;
    }
    if (lane == 0) out[it] = 1023 - (int)(g & 0xFFFFFFFFLL);
    if (lmax == g) {
      lmax = LLMIN;
      #pragma unroll
      for (int s = 0; s < 16; ++s) {
        if (kreg[s] == g) kreg[s] = LLMIN;
        lmax = kreg[s] > lmax ? kreg[s] : lmax;
      }
    }
  }
}

// XOR swizzle: conflict-free for stride-1 (staging) AND stride-8 (window) rows
static __device__ __forceinline__ int qsw(int r) { return r ^ ((r >> 3) & 7); }

// ---------------- D1: k1 (256 blocks) | kw (512 blocks), 512 thr ----------------
__global__ __launch_bounds__(512) void d1_prep(
    const float* __restrict__ q, const float* __restrict__ k,
    const float* __restrict__ w,
    float* __restrict__ Wt, float* __restrict__ amp2part) {
  __shared__ float smem[9216];          // 36 KB (main: QP 16K + Ks 16K; combine: 2x 128x36)
  int bid = blockIdx.x;
  int tid = threadIdx.x;
  if (bid < 256) {                      // ---- k1: (bh, eg) ----
    int bh = bid & 15;  int eg = bid >> 4;
    int b = bh >> 3, h = bh & 7;
    float4* QP = reinterpret_cast<float4*>(smem);        // 1024, XOR swizzle
    float4* Ks = QP + 1024;                              // 1024
    const float* qb  = q + (size_t)b*524288 + h*64 + eg*4;
    const float* kbp = k + (size_t)b*524288 + h*64 + eg*4;
    for (int r = tid; r < 1024; r += 512) {
      QP[qsw(r)] = *reinterpret_cast<const float4*>(qb  + (size_t)r*512);
      Ks[r]      = *reinterpret_cast<const float4*>(kbp + (size_t)r*512);
    }
    __syncthreads();
    int ch = tid >> 7, tg = tid & 127;  // 4 t-chunks x 128 tau-groups
    int tb = tg << 3;                   // 8 taus per thread: tb..tb+7
    int tstart = ch << 8;               // t in [tstart, tstart+256)
    float4 acc[8], wnd[8];
    #pragma unroll
    for (int i = 0; i < 8; ++i) {
      acc[i] = make_float4(0,0,0,0);
      int r = (tstart + tb + i) & 1023;
      wnd[i] = QP[qsw(r)];
    }
    for (int t8 = 0; t8 < 256; t8 += 8) {     // round-9-verified rolling loop
      #pragma unroll
      for (int s = 0; s < 8; ++s) {
        float4 kv = Ks[tstart + t8 + s];
        #pragma unroll
        for (int i = 0; i < 8; ++i)
          fma4(acc[i], wnd[(s + i) & 7], kv); // acc FIXED per tau tb+i
        int rn = (tstart + t8 + s + tb + 8) & 1023;
        wnd[s] = QP[qsw(rn)];                 // overwrite slot t&7
      }
    }
    __syncthreads();                    // QP/Ks dead; reuse for combine
    float* bufA = smem;                 // 128 rows x 36 floats
    float* bufB = smem + 4608;
    float* a = reinterpret_cast<float*>(acc);
    if (ch == 1 || ch == 3) {           // phase 1: odd chunks publish
      float* rp = (ch == 1 ? bufA : bufB) + tg*36;
      #pragma unroll
      for (int i = 0; i < 32; ++i) rp[i] = a[i];
    }
    __syncthreads();
    if (ch == 0 || ch == 2) {           // phase 2: even chunks absorb
      const float* rp = (ch == 0 ? bufA : bufB) + tg*36;
      #pragma unroll
      for (int i = 0; i < 32; ++i) a[i] += rp[i];
    }
    __syncthreads();
    if (ch == 2) {                      // phase 3: chunk2 publishes
      float* rp = bufA + tg*36;
      #pragma unroll
      for (int i = 0; i < 32; ++i) rp[i] = a[i];
    }
    __syncthreads();
    if (ch == 0) {                      // phase 4: chunk0 finalizes
      const float* rp = bufA + tg*36;
      #pragma unroll
      for (int i = 0; i < 32; ++i) a[i] += rp[i];
      float4 r0, r1;
      r0.x = acc[0].x*acc[0].x + acc[0].y*acc[0].y + acc[0].z*acc[0].z + acc[0].w*acc[0].w;
      r0.y = acc[1].x*acc[1].x + acc[1].y*acc[1].y + acc[1].z*acc[1].z + acc[1].w*acc[1].w;
      r0.z = acc[2].x*acc[2].x + acc[2].y*acc[2].y + acc[2].z*acc[2].z + acc[2].w*acc[2].w;
      r0.w = acc[3].x*acc[3].x + acc[3].y*acc[3].y + acc[3].z*acc[3].z + acc[3].w*acc[3].w;
      r1.x = acc[4].x*acc[4].x + acc[4].y*acc[4].y + acc[4].z*acc[4].z + acc[4].w*acc[4].w;
      r1.y = acc[5].x*acc[5].x + acc[5].y*acc[5].y + acc[5].z*acc[5].z + acc[5].w*acc[5].w;
      r1.z = acc[6].x*acc[6].x + acc[6].y*acc[6].y + acc[6].z*acc[6].z + acc[6].w*acc[6].w;
      r1.w = acc[7].x*acc[7].x + acc[7].y*acc[7].y + acc[7].z*acc[7].z + acc[7].w*acc[7].w;
      float4* op = reinterpret_cast<float4*>(
          amp2part + (((size_t)(bh*16 + eg)) << 10) + tb);
      op[0] = r0; op[1] = r1;
    }
  } else {                              // ---- kw ----
    int wid = bid - 256;
    int c0 = (wid & 31) << 6, r0 = (wid >> 5) << 6;
    float* tile = smem;                 // 64*65 floats
    #pragma unroll
    for (int s = 0; s < 8; ++s) {
      int idx = tid + (s << 9);
      int r = idx >> 6, c = idx & 63;
      tile[r*65 + c] = w[(size_t)(r0 + r)*2048 + c0 + c];
    }
    __syncthreads();
    #pragma unroll
    for (int s = 0; s < 8; ++s) {
      int idx = tid + (s << 9);
      int c = idx >> 6, r = idx & 63;
      Wt[(size_t)(c0 + c)*1024 + r0 + r] = tile[r*65 + c];
    }
  }
}

// ---------------- D2: top-35 both branches, 1024 threads ----------------
__global__ __launch_bounds__(1024) void d2_topk(
    const float* __restrict__ amp2part, const float* __restrict__ tfq,
    int* __restrict__ St, int* __restrict__ Stf) {
  __shared__ float vals[1024];
  int bid = blockIdx.x;
  int tid = threadIdx.x;
  bool isT = bid < 16;
  int bh = isT ? bid : bid - 16;
  if (isT) {                            // sum amp2part over eg (coalesced)
    float s = 0.f;
    #pragma unroll
    for (int eg = 0; eg < 16; ++eg)
      s += amp2part[(((size_t)(bh*16 + eg)) << 10) + tid];
    vals[tid] = s;
  } else {                              // tf row norms
    int b = bh >> 3, h = bh & 7;
    const float4* p = reinterpret_cast<const float4*>(
        tfq + (((size_t)(b*1024 + tid)*8 + h) << 6));
    float s = 0.f;
    #pragma unroll
    for (int i = 0; i < 16; ++i) {
      float4 vv = p[i];
      s += vv.x*vv.x + vv.y*vv.y + vv.z*vv.z + vv.w*vv.w;
    }
    vals[tid] = s;
  }
  __syncthreads();
  if (tid < 64) wave_top35(vals, (isT ? St : Stf) + bh*40);
}

// ---------------- D3: kb (direct Wt) | k4 ----------------
__global__ __launch_bounds__(256) void d3_mix(
    const float* __restrict__ q, const float* __restrict__ k,
    const float* __restrict__ tfq,
    const float* __restrict__ Wt, const float* __restrict__ bias,
    const float* __restrict__ values,
    const int* __restrict__ St, const int* __restrict__ Stf,
    float* __restrict__ WVp, float* __restrict__ P) {
  __shared__ float4 smbuf[1712];        // 27392 B (k4); kb uses first 4 KB
  float* f = reinterpret_cast<float*>(smbuf);
  int bid = blockIdx.x;
  int tid = threadIdx.x;
  if (bid < 1152) {                     // ---- kb: WVp partial, direct Wt ----
    int jq = bid / 64;                  // 0..17
    int rem = bid - jq*64;
    int bh = rem >> 2, mc = rem & 3;
    int b = bh >> 3, h = bh & 7;
    int j0 = jq << 2;
    const float* pj[4];
    #pragma unroll
    for (int x = 0; x < 4; ++x) {
      int j = j0 + x;
      if (j < NTOP)      pj[x] = Wt + (size_t)St [bh*40 + j]*1024;
      else if (j < NJ)   pj[x] = Wt + (size_t)(1024 + Stf[bh*40 + j-NTOP])*1024;
      else if (j == NJ)  pj[x] = bias;
      else               pj[x] = Wt;    // j==71: garbage, zeroed in epilogue
    }
    int d = tid & 63, mp = tid >> 6;
    int m0 = (mc << 8) + mp;
    float a0=0.f, a1=0.f, a2=0.f, a3=0.f;
    #pragma unroll 16
    for (int i = 0; i < 64; ++i) {
      int m = m0 + (i << 2);
      float vv = values[(((size_t)(b*1024 + m)*8 + h) << 6) + d];
      a0 = fmaf(pj[0][m], vv, a0);
      a1 = fmaf(pj[1][m], vv, a1);
      a2 = fmaf(pj[2][m], vv, a2);
      a3 = fmaf(pj[3][m], vv, a3);
    }
    float4* red = smbuf;
    red[tid] = make_float4(a0, a1, a2, a3);
    __syncthreads();
    int jj = tid >> 6, dd = tid & 63;
    float4 r0 = red[dd], r1 = red[64+dd], r2 = red[128+dd], r3 = red[192+dd];
    float s;
    if (jj == 0)      s = r0.x + r1.x + r2.x + r3.x;
    else if (jj == 1) s = r0.y + r1.y + r2.y + r3.y;
    else if (jj == 2) s = r0.z + r1.z + r2.z + r3.z;
    else              s = r0.w + r1.w + r2.w + r3.w;
    if (j0 + jj > NJ) s = 0.f;
    WVp[(size_t)mc*73728 + ((size_t)bh*72 + j0 + jj)*64 + dd] = s;
  } else {                              // ---- k4 ----
    int gid = bid - 1152;
    int bh = gid >> 5;  int m0 = (gid & 31) << 5;
    int b = bh >> 3, h = bh & 7;
    float* qs   = f;                    // 35*64
    float* ts   = f + 2240;
    float* sc   = f + 4480;             // 32*73
    float* invs = f + 6816;             // 32
    for (int i = tid; i < NTOP*64; i += 256) {
      int j = i >> 6, e = i & 63;
      qs[i] = q  [(((size_t)(b*1024 + St [bh*40 + j])*8 + h) << 6) + e];
      ts[i] = tfq[(((size_t)(b*1024 + Stf[bh*40 + j])*8 + h) << 6) + e];
    }
    __syncthreads();
    int mi = tid & 31, g = tid >> 5;
    int br = g >> 2, g4 = g & 3;
    int m = m0 + mi;
    const float* src = br ? tfq : k;
    float4 kr[16];
    const float4* p = reinterpret_cast<const float4*>(
        src + (((size_t)(b*1024 + m)*8 + h) << 6));
    #pragma unroll
    for (int i = 0; i < 16; ++i) kr[i] = p[i];
    const float4* fs4 = reinterpret_cast<const float4*>(br ? ts : qs);
    int sb = br ? NTOP : 0;
    for (int j = g4; j < NTOP; j += 4) {
      float s = 0.f;
      #pragma unroll
      for (int e4 = 0; e4 < 16; ++e4) {
        float4 qv = fs4[j*16 + e4];
        s += qv.x*kr[e4].x + qv.y*kr[e4].y + qv.z*kr[e4].z + qv.w*kr[e4].w;
      }
      sc[mi*73 + sb + j] = s * 0.125f;
    }
    __syncthreads();
    if (tid < 32) {
      float mx = -1e30f;
      for (int j = 0; j < NJ; ++j) mx = fmaxf(mx, sc[tid*73 + j]);
      float sum = 0.f;
      for (int j = 0; j < NJ; ++j) {
        float e = __expf(sc[tid*73 + j] - mx);
        sc[tid*73 + j] = e; sum += e;
      }
      invs[tid] = 1.0f / sum;
    }
    __syncthreads();
    float* Pb = P + ((size_t)bh*1024 + m0)*72;
    for (int i = tid; i < 32*72; i += 256) {
      int mm = i / 72, j = i - mm*72;
      Pb[i] = (j < NJ) ? sc[mm*73 + j] * invs[mm] : 0.f;
    }
  }
}

// ---------------- D4: k6 per-bh, LDS Wv + transposed P chunk ----------------
__global__ __launch_bounds__(256) void k6_out(
    const float* __restrict__ P, const float* __restrict__ WVp,
    float* __restrict__ out) {
  __shared__ float wv[72*64];           // 18432 B
  __shared__ float Pl[72*68];           // 19584 B
  int bh = blockIdx.x, lc = blockIdx.y;
  int l0 = lc << 6;
  int b = bh >> 3, h = bh & 7;
  int tid = threadIdx.x;
  {
    const float* W0 = WVp + (size_t)bh*4608;
    for (int i = tid; i < 4608; i += 256)
      wv[i] = W0[i] + W0[73728 + i] + W0[147456 + i] + W0[221184 + i];
  }
  {
    const float* Pg = P + ((size_t)bh*1024 + l0)*72;
    for (int i = tid; i < 4608; i += 256) {
      int l = i / 72, j = i - l*72;
      Pl[j*68 + l] = Pg[i];
    }
  }
  __syncthreads();
  int d = tid & 63, lg = tid >> 6;
  int lb = lg << 4;
  float acc[16];
  float base = wv[NJ*64 + d];
  #pragma unroll
  for (int i = 0; i < 16; ++i) acc[i] = base;
  for (int j = 0; j < NJ; ++j) {
    float wvj = wv[j*64 + d];
    const float4* pr = reinterpret_cast<const float4*>(Pl + j*68 + lb);
    float4 p0 = pr[0], p1 = pr[1], p2 = pr[2], p3 = pr[3];
    acc[0]  = fmaf(p0.x, wvj, acc[0]);  acc[1]  = fmaf(p0.y, wvj, acc[1]);
    acc[2]  = fmaf(p0.z, wvj, acc[2]);  acc[3]  = fmaf(p0.w, wvj, acc[3]);
    acc[4]  = fmaf(p1.x, wvj, acc[4]);  acc[5]  = fmaf(p1.y, wvj, acc[5]);
    acc[6]  = fmaf(p1.z, wvj, acc[6]);  acc[7]  = fmaf(p1.w, wvj, acc[7]);
    acc[8]  = fmaf(p2.x, wvj, acc[8]);  acc[9]  = fmaf(p2.y, wvj, acc[9]);
    acc[10] = fmaf(p2.z, wvj, acc[10]); acc[11] = fmaf(p2.w, wvj, acc[11]);
    acc[12] = fmaf(p3.x, wvj, acc[12]); acc[13] = fmaf(p3.y, wvj, acc[13]);
    acc[14] = fmaf(p3.z, wvj, acc[14]); acc[15] = fmaf(p3.w, wvj, acc[15]);
  }
  #pragma unroll
  for (int i = 0; i < 16; ++i) {
    int l = l0 + lb + i;
    out[(((size_t)(b*1024 + l)*8 + h) << 6) + d] = acc[i];
  }
}

extern "C" void kernel_launch(void* const* d_in, const int* in_sizes, int n_in,
                              void* d_out, int out_size, void* d_ws, size_t ws_size,
                              hipStream_t stream) {
  const float* tfq  = (const float*)d_in[0];
  const float* q    = (const float*)d_in[1];
  const float* k    = (const float*)d_in[2];
  const float* v    = (const float*)d_in[3];
  const float* tw   = (const float*)d_in[5];
  const float* tb   = (const float*)d_in[6];
  float* out = (float*)d_out;

  char* ws = (char*)d_ws;
  float* amp2part = (float*)(ws);                   // 1,048,576
  int*   St  = (int*)  (ws + 1048576);              // 4 KB
  int*   Stf = (int*)  (ws + 1052672);              // 4 KB
  float* Wt  = (float*)(ws + 1056768);              // 8,388,608
  float* P   = (float*)(ws + 9445376);              // 4,718,592
  float* WVp = (float*)(ws + 14163968);             // 1,179,648

  d1_prep<<<768, 512, 0, stream>>>(q, k, tw, Wt, amp2part);
  d2_topk<<<32, 1024, 0, stream>>>(amp2part, tfq, St, Stf);
  d3_mix <<<1664, 256, 0, stream>>>(q, k, tfq, Wt, tb, v, St, Stf, WVp, P);
  k6_out <<<dim3(16, 16), 256, 0, stream>>>(P, WVp, out);
}

// Round 13
// 184.540 us; speedup vs baseline: 1.0935x; 1.0050x over previous
//
#include <hip/hip_runtime.h>

// MixSelfAttention (B=2, L=1024, H=8, E=64), float32 in/out. 4 dispatches:
//   D1 d1: k1 circular-corr per (bh,eg) block, 512 thr = 8 t-chunks x 64 tau-grp,
//          16 taus/thread (halved LDS traffic), XOR16 swizzle, 3-level LDS
//          chunk-combine -> amp2part[bh][eg][tau] (1 MB)  (blocks 0..255)
//          | kw tile-transpose W -> Wt[2048][1024] (blocks 256..767)
//   D2 d2: 32 blocks x 1024 thr; t: sum amp2part over eg + top35 -> St
//          tf: row norms + top35 -> Stf (single-wave selection)
//   D3 d3: kb direct-Wt WVp partials (0..1151) | k4 scores+softmax -> P (1152..1663)
//   D4 k6: per-bh blocks, 512 thr; Wv=sum_mc WVp staged in LDS + transposed P

#define NTOP 35
#define NJ 70
#define LLMIN (-0x7FFFFFFFFFFFFFFFLL - 1)

static __device__ __forceinline__ void fma4(float4& a, float4 q, float4 k) {
  a.x = fmaf(q.x,k.x,a.x); a.y = fmaf(q.y,k.y,a.y);
  a.z = fmaf(q.z,k.z,a.z); a.w = fmaf(q.w,k.w,a.w);
}
static __device__ __forceinline__ void fadd4(float4& a, float4 b) {
  a.x += b.x; a.y += b.y; a.z += b.z; a.w += b.w;
}

// single-wave top-35 (threadIdx.x<64 calls), vals[1024] ready, jax tie-break
static __device__ __forceinline__ void wave_top35(const float* vals, int* out) {
  int lane = threadIdx.x;
  long long kreg[16];
  long long lmax = LLMIN;
  #pragma unroll
  for (int s = 0; s < 16; ++s) {
    int l = (s << 6) + lane;
    long long key = ((long long)(int)__float_as_uint(vals[l]) << 32)
                    | (unsigned int)(1023 - l);
    kreg[s] = key;
    lmax = key > lmax ? key : lmax;
  }
  for (int it = 0; it < NTOP; ++it) {
    long long g = lmax;
    #pragma unroll
    for (int off = 1; off < 64; off <<= 1) {
      long long o = __shfl_xor(g, off);
      g = o > g ? o : g;
    }
    if (lane == 0) out[it] = 1023 - (int)(g & 0xFFFFFFFFLL);
    if (lmax == g) {
      lmax = LLMIN;
      #pragma unroll
      for (int s = 0; s < 16; ++s) {
        if (kreg[s] == g) kreg[s] = LLMIN;
        lmax = kreg[s] > lmax ? kreg[s] : lmax;
      }
    }
  }
}

// XOR16 swizzle: conflict-free for stride-1 (staging) AND stride-16 (window)
static __device__ __forceinline__ int qsw(int r) { return r ^ ((r >> 4) & 7); }

// ---------------- D1: k1 (256 blocks) | kw (512 blocks), 512 thr ----------------
__global__ __launch_bounds__(512) void d1_prep(
    const float* __restrict__ q, const float* __restrict__ k,
    const float* __restrict__ w,
    float* __restrict__ Wt, float* __restrict__ amp2part) {
  __shared__ float smem[9216];          // 36 KB (main: QP 16K + Ks 16K; combine tree)
  int bid = blockIdx.x;
  int tid = threadIdx.x;
  if (bid < 256) {                      // ---- k1: (bh, eg) ----
    int bh = bid & 15;  int eg = bid >> 4;
    int b = bh >> 3, h = bh & 7;
    float4* QP = reinterpret_cast<float4*>(smem);        // 1024, XOR16 swizzle
    float4* Ks = QP + 1024;                              // 1024
    const float* qb  = q + (size_t)b*524288 + h*64 + eg*4;
    const float* kbp = k + (size_t)b*524288 + h*64 + eg*4;
    for (int r = tid; r < 1024; r += 512) {
      QP[qsw(r)] = *reinterpret_cast<const float4*>(qb  + (size_t)r*512);
      Ks[r]      = *reinterpret_cast<const float4*>(kbp + (size_t)r*512);
    }
    __syncthreads();
    int ch = tid >> 6, tg = tid & 63;   // 8 t-chunks x 64 tau-groups
    int tb = tg << 4;                   // 16 taus per thread: tb..tb+15
    int tstart = ch << 7;               // t in [tstart, tstart+128)
    float4 acc[16], wnd[16];
    #pragma unroll
    for (int i = 0; i < 16; ++i) {
      acc[i] = make_float4(0,0,0,0);
      int r = (tstart + tb + i) & 1023;
      wnd[i] = QP[qsw(r)];
    }
    for (int t8 = 0; t8 < 128; t8 += 16) {
      #pragma unroll
      for (int s = 0; s < 16; ++s) {
        float4 kv = Ks[tstart + t8 + s];
        #pragma unroll
        for (int i = 0; i < 16; ++i)
          fma4(acc[i], wnd[(s + i) & 15], kv);  // acc FIXED per tau tb+i
        int rn = (tstart + t8 + s + tb + 16) & 1023;
        wnd[s] = QP[qsw(rn)];                   // overwrite slot t&15
      }
    }
    __syncthreads();                    // QP/Ks dead; reuse for combine tree
    float4* xb = reinterpret_cast<float4*>(smem);   // 2304 float4
    // Level 1 (ch 4..7 -> ch 0..3), two 8-f4 halves, rows of 9 f4
    #pragma unroll
    for (int half = 0; half < 2; ++half) {
      if (ch >= 4) {
        float4* rp = xb + (ch - 4)*576 + tg*9;
        #pragma unroll
        for (int i = 0; i < 8; ++i) rp[i] = acc[half*8 + i];
      }
      __syncthreads();
      if (ch < 4) {
        const float4* rp = xb + ch*576 + tg*9;
        #pragma unroll
        for (int i = 0; i < 8; ++i) fadd4(acc[half*8 + i], rp[i]);
      }
      __syncthreads();
    }
    // Level 2 (ch 2,3 -> ch 0,1), full 16 f4, rows of 17 f4
    if (ch == 2 || ch == 3) {
      float4* rp = xb + (ch - 2)*1088 + tg*17;
      #pragma unroll
      for (int i = 0; i < 16; ++i) rp[i] = acc[i];
    }
    __syncthreads();
    if (ch < 2) {
      const float4* rp = xb + ch*1088 + tg*17;
      #pragma unroll
      for (int i = 0; i < 16; ++i) fadd4(acc[i], rp[i]);
    }
    __syncthreads();
    // Level 3 (ch 1 -> ch 0)
    if (ch == 1) {
      float4* rp = xb + tg*17;
      #pragma unroll
      for (int i = 0; i < 16; ++i) rp[i] = acc[i];
    }
    __syncthreads();
    if (ch == 0) {
      const float4* rp = xb + tg*17;
      #pragma unroll
      for (int i = 0; i < 16; ++i) fadd4(acc[i], rp[i]);
      float4 r[4];
      #pragma unroll
      for (int m = 0; m < 4; ++m) {
        float4 a0 = acc[4*m], a1 = acc[4*m+1], a2 = acc[4*m+2], a3 = acc[4*m+3];
        r[m].x = a0.x*a0.x + a0.y*a0.y + a0.z*a0.z + a0.w*a0.w;
        r[m].y = a1.x*a1.x + a1.y*a1.y + a1.z*a1.z + a1.w*a1.w;
        r[m].z = a2.x*a2.x + a2.y*a2.y + a2.z*a2.z + a2.w*a2.w;
        r[m].w = a3.x*a3.x + a3.y*a3.y + a3.z*a3.z + a3.w*a3.w;
      }
      float4* op = reinterpret_cast<float4*>(
          amp2part + (((size_t)(bh*16 + eg)) << 10) + tb);
      op[0] = r[0]; op[1] = r[1]; op[2] = r[2]; op[3] = r[3];
    }
  } else {                              // ---- kw ----
    int wid = bid - 256;
    int c0 = (wid & 31) << 6, r0 = (wid >> 5) << 6;
    float* tile = smem;                 // 64*65 floats
    #pragma unroll
    for (int s = 0; s < 8; ++s) {
      int idx = tid + (s << 9);
      int r = idx >> 6, c = idx & 63;
      tile[r*65 + c] = w[(size_t)(r0 + r)*2048 + c0 + c];
    }
    __syncthreads();
    #pragma unroll
    for (int s = 0; s < 8; ++s) {
      int idx = tid + (s << 9);
      int c = idx >> 6, r = idx & 63;
      Wt[(size_t)(c0 + c)*1024 + r0 + r] = tile[r*65 + c];
    }
  }
}

// ---------------- D2: top-35 both branches, 1024 threads ----------------
__global__ __launch_bounds__(1024) void d2_topk(
    const float* __restrict__ amp2part, const float* __restrict__ tfq,
    int* __restrict__ St, int* __restrict__ Stf) {
  __shared__ float vals[1024];
  int bid = blockIdx.x;
  int tid = threadIdx.x;
  bool isT = bid < 16;
  int bh = isT ? bid : bid - 16;
  if (isT) {                            // sum amp2part over eg (coalesced)
    float s = 0.f;
    #pragma unroll
    for (int eg = 0; eg < 16; ++eg)
      s += amp2part[(((size_t)(bh*16 + eg)) << 10) + tid];
    vals[tid] = s;
  } else {                              // tf row norms
    int b = bh >> 3, h = bh & 7;
    const float4* p = reinterpret_cast<const float4*>(
        tfq + (((size_t)(b*1024 + tid)*8 + h) << 6));
    float s = 0.f;
    #pragma unroll
    for (int i = 0; i < 16; ++i) {
      float4 vv = p[i];
      s += vv.x*vv.x + vv.y*vv.y + vv.z*vv.z + vv.w*vv.w;
    }
    vals[tid] = s;
  }
  __syncthreads();
  if (tid < 64) wave_top35(vals, (isT ? St : Stf) + bh*40);
}

// ---------------- D3: kb (direct Wt) | k4 ----------------
__global__ __launch_bounds__(256) void d3_mix(
    const float* __restrict__ q, const float* __restrict__ k,
    const float* __restrict__ tfq,
    const float* __restrict__ Wt, const float* __restrict__ bias,
    const float* __restrict__ values,
    const int* __restrict__ St, const int* __restrict__ Stf,
    float* __restrict__ WVp, float* __restrict__ P) {
  __shared__ float4 smbuf[1712];        // 27392 B (k4); kb uses first 4 KB
  float* f = reinterpret_cast<float*>(smbuf);
  int bid = blockIdx.x;
  int tid = threadIdx.x;
  if (bid < 1152) {                     // ---- kb: WVp partial, direct Wt ----
    int jq = bid / 64;                  // 0..17
    int rem = bid - jq*64;
    int bh = rem >> 2, mc = rem & 3;
    int b = bh >> 3, h = bh & 7;
    int j0 = jq << 2;
    const float* pj[4];
    #pragma unroll
    for (int x = 0; x < 4; ++x) {
      int j = j0 + x;
      if (j < NTOP)      pj[x] = Wt + (size_t)St [bh*40 + j]*1024;
      else if (j < NJ)   pj[x] = Wt + (size_t)(1024 + Stf[bh*40 + j-NTOP])*1024;
      else if (j == NJ)  pj[x] = bias;
      else               pj[x] = Wt;    // j==71: garbage, zeroed in epilogue
    }
    int d = tid & 63, mp = tid >> 6;
    int m0 = (mc << 8) + mp;
    float a0=0.f, a1=0.f, a2=0.f, a3=0.f;
    #pragma unroll 16
    for (int i = 0; i < 64; ++i) {
      int m = m0 + (i << 2);
      float vv = values[(((size_t)(b*1024 + m)*8 + h) << 6) + d];
      a0 = fmaf(pj[0][m], vv, a0);
      a1 = fmaf(pj[1][m], vv, a1);
      a2 = fmaf(pj[2][m], vv, a2);
      a3 = fmaf(pj[3][m], vv, a3);
    }
    float4* red = smbuf;
    red[tid] = make_float4(a0, a1, a2, a3);
    __syncthreads();
    int jj = tid >> 6, dd = tid & 63;
    float4 r0 = red[dd], r1 = red[64+dd], r2 = red[128+dd], r3 = red[192+dd];
    float s;
    if (jj == 0)      s = r0.x + r1.x + r2.x + r3.x;
    else if (jj == 1) s = r0.y + r1.y + r2.y + r3.y;
    else if (jj == 2) s = r0.z + r1.z + r2.z + r3.z;
    else              s = r0.w + r1.w + r2.w + r3.w;
    if (j0 + jj > NJ) s = 0.f;
    WVp[(size_t)mc*73728 + ((size_t)bh*72 + j0 + jj)*64 + dd] = s;
  } else {                              // ---- k4 ----
    int gid = bid - 1152;
    int bh = gid >> 5;  int m0 = (gid & 31) << 5;
    int b = bh >> 3, h = bh & 7;
    float* qs   = f;                    // 35*64
    float* ts   = f + 2240;
    float* sc   = f + 4480;             // 32*73
    float* invs = f + 6816;             // 32
    for (int i = tid; i < NTOP*64; i += 256) {
      int j = i >> 6, e = i & 63;
      qs[i] = q  [(((size_t)(b*1024 + St [bh*40 + j])*8 + h) << 6) + e];
      ts[i] = tfq[(((size_t)(b*1024 + Stf[bh*40 + j])*8 + h) << 6) + e];
    }
    __syncthreads();
    int mi = tid & 31, g = tid >> 5;
    int br = g >> 2, g4 = g & 3;
    int m = m0 + mi;
    const float* src = br ? tfq : k;
    float4 kr[16];
    const float4* p = reinterpret_cast<const float4*>(
        src + (((size_t)(b*1024 + m)*8 + h) << 6));
    #pragma unroll
    for (int i = 0; i < 16; ++i) kr[i] = p[i];
    const float4* fs4 = reinterpret_cast<const float4*>(br ? ts : qs);
    int sb = br ? NTOP : 0;
    for (int j = g4; j < NTOP; j += 4) {
      float s = 0.f;
      #pragma unroll
      for (int e4 = 0; e4 < 16; ++e4) {
        float4 qv = fs4[j*16 + e4];
        s += qv.x*kr[e4].x + qv.y*kr[e4].y + qv.z*kr[e4].z + qv.w*kr[e4].w;
      }
      sc[mi*73 + sb + j] = s * 0.125f;
    }
    __syncthreads();
    if (tid < 32) {
      float mx = -1e30f;
      for (int j = 0; j < NJ; ++j) mx = fmaxf(mx, sc[tid*73 + j]);
      float sum = 0.f;
      for (int j = 0; j < NJ; ++j) {
        float e = __expf(sc[tid*73 + j] - mx);
        sc[tid*73 + j] = e; sum += e;
      }
      invs[tid] = 1.0f / sum;
    }
    __syncthreads();
    float* Pb = P + ((size_t)bh*1024 + m0)*72;
    for (int i = tid; i < 32*72; i += 256) {
      int mm = i / 72, j = i - mm*72;
      Pb[i] = (j < NJ) ? sc[mm*73 + j] * invs[mm] : 0.f;
    }
  }
}

// ---------------- D4: k6 per-bh, 512 thr, LDS Wv + transposed P chunk ----------------
__global__ __launch_bounds__(512) void k6_out(
    const float* __restrict__ P, const float* __restrict__ WVp,
    float* __restrict__ out) {
  __shared__ float wv[72*64];           // 18432 B
  __shared__ float Pl[72*68];           // 19584 B
  int bh = blockIdx.x, lc = blockIdx.y;
  int l0 = lc << 6;
  int b = bh >> 3, h = bh & 7;
  int tid = threadIdx.x;
  {
    const float* W0 = WVp + (size_t)bh*4608;
    for (int i = tid; i < 4608; i += 512)
      wv[i] = W0[i] + W0[73728 + i] + W0[147456 + i] + W0[221184 + i];
  }
  {
    const float* Pg = P + ((size_t)bh*1024 + l0)*72;
    for (int i = tid; i < 4608; i += 512) {
      int l = i / 72, j = i - l*72;
      Pl[j*68 + l] = Pg[i];
    }
  }
  __syncthreads();
  int d = tid & 63, lg = tid >> 6;      // 8 l-groups of 8
  int lb = lg << 3;
  float acc[8];
  float base = wv[NJ*64 + d];
  #pragma unroll
  for (int i = 0; i < 8; ++i) acc[i] = base;
  for (int j = 0; j < NJ; ++j) {
    float wvj = wv[j*64 + d];
    const float4* pr = reinterpret_cast<const float4*>(Pl + j*68 + lb);
    float4 p0 = pr[0], p1 = pr[1];
    acc[0] = fmaf(p0.x, wvj, acc[0]); acc[1] = fmaf(p0.y, wvj, acc[1]);
    acc[2] = fmaf(p0.z, wvj, acc[2]); acc[3] = fmaf(p0.w, wvj, acc[3]);
    acc[4] = fmaf(p1.x, wvj, acc[4]); acc[5] = fmaf(p1.y, wvj, acc[5]);
    acc[6] = fmaf(p1.z, wvj, acc[6]); acc[7] = fmaf(p1.w, wvj, acc[7]);
  }
  #pragma unroll
  for (int i = 0; i < 8; ++i) {
    int l = l0 + lb + i;
    out[(((size_t)(b*1024 + l)*8 + h) << 6) + d] = acc[i];
  }
}

extern "C" void kernel_launch(void* const* d_in, const int* in_sizes, int n_in,
                              void* d_out, int out_size, void* d_ws, size_t ws_size,
                              hipStream_t stream) {
  const float* tfq  = (const float*)d_in[0];
  const float* q    = (const float*)d_in[1];
  const float* k    = (const float*)d_in[2];
  const float* v    = (const float*)d_in[3];
  const float* tw   = (const float*)d_in[5];
  const float* tb   = (const float*)d_in[6];
  float* out = (float*)d_out;

  char* ws = (char*)d_ws;
  float* amp2part = (float*)(ws);                   // 1,048,576
  int*   St  = (int*)  (ws + 1048576);              // 4 KB
  int*   Stf = (int*)  (ws + 1052672);              // 4 KB
  float* Wt  = (float*)(ws + 1056768);              // 8,388,608
  float* P   = (float*)(ws + 9445376);              // 4,718,592
  float* WVp = (float*)(ws + 14163968);             // 1,179,648

  d1_prep<<<768, 512, 0, stream>>>(q, k, tw, Wt, amp2part);
  d2_topk<<<32, 1024, 0, stream>>>(amp2part, tfq, St, Stf);
  d3_mix <<<1664, 256, 0, stream>>>(q, k, tfq, Wt, tb, v, St, Stf, WVp, P);
  k6_out <<<dim3(16, 16), 512, 0, stream>>>(P, WVp, out);
}

// Round 14
// 176.854 us; speedup vs baseline: 1.1410x; 1.0435x over previous
//
#include <hip/hip_runtime.h>

// MixSelfAttention (B=2, L=1024, H=8, E=64), float32 in/out. 4 dispatches:
//   D1 d1: k1 circular-corr partials, 1024 blocks (bh x eg x tc256), 256 thr =
//          4 t-subchunks x 64 tau-grp, 16 taus/thread, XOR16-swizzled LDS,
//          in-block sub-combine -> acp[be][tc][tau][4e] raw partials (16 MB)
//          | kw tile-transpose W -> Wt[2048][1024] (blocks 1024..1535)
//   D2 d2: 32 blocks x 1024 thr; t: tc-combine+square+e-sum + top35 -> St
//          tf: row norms + top35 -> Stf (single-wave selection)
//   D3 d3: kb direct-Wt WVp partials (0..1151) | k4 scores+softmax -> P (1152..1663)
//   D4 k6: per-bh blocks, 512 thr; Wv=sum_mc WVp staged in LDS + transposed P

#define NTOP 35
#define NJ 70
#define LLMIN (-0x7FFFFFFFFFFFFFFFLL - 1)

static __device__ __forceinline__ void fma4(float4& a, float4 q, float4 k) {
  a.x = fmaf(q.x,k.x,a.x); a.y = fmaf(q.y,k.y,a.y);
  a.z = fmaf(q.z,k.z,a.z); a.w = fmaf(q.w,k.w,a.w);
}
static __device__ __forceinline__ void fadd4(float4& a, float4 b) {
  a.x += b.x; a.y += b.y; a.z += b.z; a.w += b.w;
}

// single-wave top-35 (threadIdx.x<64 calls), vals[1024] ready, jax tie-break
static __device__ __forceinline__ void wave_top35(const float* vals, int* out) {
  int lane = threadIdx.x;
  long long kreg[16];
  long long lmax = LLMIN;
  #pragma unroll
  for (int s = 0; s < 16; ++s) {
    int l = (s << 6) + lane;
    long long key = ((long long)(int)__float_as_uint(vals[l]) << 32)
                    | (unsigned int)(1023 - l);
    kreg[s] = key;
    lmax = key > lmax ? key : lmax;
  }
  for (int it = 0; it < NTOP; ++it) {
    long long g = lmax;
    #pragma unroll
    for (int off = 1; off < 64; off <<= 1) {
      long long o = __shfl_xor(g, off);
      g = o > g ? o : g;
    }
    if (lane == 0) out[it] = 1023 - (int)(g & 0xFFFFFFFFLL);
    if (lmax == g) {
      lmax = LLMIN;
      #pragma unroll
      for (int s = 0; s < 16; ++s) {
        if (kreg[s] == g) kreg[s] = LLMIN;
        lmax = kreg[s] > lmax ? kreg[s] : lmax;
      }
    }
  }
}

// XOR16 swizzle: conflict-free for stride-1 (staging) AND stride-16 (window)
static __device__ __forceinline__ int qsw(int r) { return r ^ ((r >> 4) & 7); }

// ---------------- D1: k1 (1024 blocks) | kw (512 blocks), 256 thr ----------------
__global__ __launch_bounds__(256) void d1_prep(
    const float* __restrict__ q, const float* __restrict__ k,
    const float* __restrict__ w,
    float* __restrict__ Wt, float* __restrict__ acp) {
  __shared__ float smem[5200];          // 20.8 KB: QP 1024 f4 + Ks 256 f4 / kw tile
  int bid = blockIdx.x;
  int tid = threadIdx.x;
  if (bid < 1024) {                     // ---- k1: (bh, eg, tc) ----
    int bh = bid & 15;  int eg = (bid >> 4) & 15;  int tc = bid >> 8;
    int b = bh >> 3, h = bh & 7;
    float4* QP = reinterpret_cast<float4*>(smem);        // 1024, XOR16 swizzle
    float4* Ks = QP + 1024;                              // 256 (this tc's t's)
    const float* qb  = q + (size_t)b*524288 + h*64 + eg*4;
    const float* kbp = k + (size_t)b*524288 + h*64 + eg*4;
    for (int r = tid; r < 1024; r += 256)
      QP[qsw(r)] = *reinterpret_cast<const float4*>(qb + (size_t)r*512);
    Ks[tid] = *reinterpret_cast<const float4*>(kbp + (size_t)((tc << 8) + tid)*512);
    __syncthreads();
    int sub = tid >> 6, tg = tid & 63;  // 4 t-subchunks x 64 tau-groups
    int tb = tg << 4;                   // 16 taus per thread
    int tstart = (tc << 8) + (sub << 6);// absolute t in [tstart, tstart+64)
    float4 acc[16], wnd[16];
    #pragma unroll
    for (int i = 0; i < 16; ++i) {
      acc[i] = make_float4(0,0,0,0);
      int r = (tstart + tb + i) & 1023;
      wnd[i] = QP[qsw(r)];
    }
    int ksb = sub << 6;
    for (int t8 = 0; t8 < 64; t8 += 16) {
      #pragma unroll
      for (int s = 0; s < 16; ++s) {
        float4 kv = Ks[ksb + t8 + s];
        #pragma unroll
        for (int i = 0; i < 16; ++i)
          fma4(acc[i], wnd[(s + i) & 15], kv);  // acc FIXED per tau tb+i
        int rn = (tstart + t8 + s + tb + 16) & 1023;
        wnd[s] = QP[qsw(rn)];                   // overwrite slot t&15
      }
    }
    __syncthreads();                    // QP/Ks dead; reuse for combine tree
    float4* xb = reinterpret_cast<float4*>(smem);   // 1300 f4 avail; use 1152
    // Level 1 (sub 2->0, 3->1), two 8-f4 halves, rows of 9 f4
    #pragma unroll
    for (int half = 0; half < 2; ++half) {
      if (sub >= 2) {
        float4* rp = xb + (sub - 2)*576 + tg*9;
        #pragma unroll
        for (int i = 0; i < 8; ++i) rp[i] = acc[half*8 + i];
      }
      __syncthreads();
      if (sub < 2) {
        const float4* rp = xb + sub*576 + tg*9;
        #pragma unroll
        for (int i = 0; i < 8; ++i) fadd4(acc[half*8 + i], rp[i]);
      }
      __syncthreads();
    }
    // Level 2 (sub 1 -> 0), two halves
    #pragma unroll
    for (int half = 0; half < 2; ++half) {
      if (sub == 1) {
        float4* rp = xb + tg*9;
        #pragma unroll
        for (int i = 0; i < 8; ++i) rp[i] = acc[half*8 + i];
      }
      __syncthreads();
      if (sub == 0) {
        const float4* rp = xb + tg*9;
        #pragma unroll
        for (int i = 0; i < 8; ++i) fadd4(acc[half*8 + i], rp[i]);
      }
      __syncthreads();
    }
    if (sub == 0) {                     // raw 4e partials for this tc chunk
      float4* op = reinterpret_cast<float4*>(acp)
                 + (((size_t)((bh*16 + eg)*4 + tc)) << 10) + tb;
      #pragma unroll
      for (int i = 0; i < 16; ++i) op[i] = acc[i];
    }
  } else {                              // ---- kw ----
    int wid = bid - 1024;
    int c0 = (wid & 31) << 6, r0 = (wid >> 5) << 6;
    float* tile = smem;                 // 64*65 floats
    #pragma unroll
    for (int s = 0; s < 16; ++s) {
      int idx = tid + (s << 8);
      int r = idx >> 6, c = idx & 63;
      tile[r*65 + c] = w[(size_t)(r0 + r)*2048 + c0 + c];
    }
    __syncthreads();
    #pragma unroll
    for (int s = 0; s < 16; ++s) {
      int idx = tid + (s << 8);
      int c = idx >> 6, r = idx & 63;
      Wt[(size_t)(c0 + c)*1024 + r0 + r] = tile[r*65 + c];
    }
  }
}

// ---------------- D2: top-35 both branches, 1024 threads ----------------
__global__ __launch_bounds__(1024) void d2_topk(
    const float* __restrict__ acp, const float* __restrict__ tfq,
    int* __restrict__ St, int* __restrict__ Stf) {
  __shared__ float vals[1024];
  int bid = blockIdx.x;
  int tid = threadIdx.x;
  bool isT = bid < 16;
  int bh = isT ? bid : bid - 16;
  if (isT) {                            // t: combine tc chunks, square, sum e
    int tau = tid;
    const float4* A = reinterpret_cast<const float4*>(acp);
    float s = 0.f;
    #pragma unroll
    for (int eg = 0; eg < 16; ++eg) {
      const float4* E = A + (((size_t)(bh*16 + eg)) << 12);
      float4 c0 = E[tau], c1 = E[1024+tau], c2 = E[2048+tau], c3 = E[3072+tau];
      float x = c0.x+c1.x+c2.x+c3.x;
      float y = c0.y+c1.y+c2.y+c3.y;
      float z = c0.z+c1.z+c2.z+c3.z;
      float w = c0.w+c1.w+c2.w+c3.w;
      s += x*x + y*y + z*z + w*w;
    }
    vals[tau] = s;
  } else {                              // tf: row norms
    int b = bh >> 3, h = bh & 7;
    const float4* p = reinterpret_cast<const float4*>(
        tfq + (((size_t)(b*1024 + tid)*8 + h) << 6));
    float s = 0.f;
    #pragma unroll
    for (int i = 0; i < 16; ++i) {
      float4 vv = p[i];
      s += vv.x*vv.x + vv.y*vv.y + vv.z*vv.z + vv.w*vv.w;
    }
    vals[tid] = s;
  }
  __syncthreads();
  if (tid < 64) wave_top35(vals, (isT ? St : Stf) + bh*40);
}

// ---------------- D3: kb (direct Wt) | k4 ----------------
__global__ __launch_bounds__(256) void d3_mix(
    const float* __restrict__ q, const float* __restrict__ k,
    const float* __restrict__ tfq,
    const float* __restrict__ Wt, const float* __restrict__ bias,
    const float* __restrict__ values,
    const int* __restrict__ St, const int* __restrict__ Stf,
    float* __restrict__ WVp, float* __restrict__ P) {
  __shared__ float4 smbuf[1712];        // 27392 B (k4); kb uses first 4 KB
  float* f = reinterpret_cast<float*>(smbuf);
  int bid = blockIdx.x;
  int tid = threadIdx.x;
  if (bid < 1152) {                     // ---- kb: WVp partial, direct Wt ----
    int jq = bid / 64;                  // 0..17
    int rem = bid - jq*64;
    int bh = rem >> 2, mc = rem & 3;
    int b = bh >> 3, h = bh & 7;
    int j0 = jq << 2;
    const float* pj[4];
    #pragma unroll
    for (int x = 0; x < 4; ++x) {
      int j = j0 + x;
      if (j < NTOP)      pj[x] = Wt + (size_t)St [bh*40 + j]*1024;
      else if (j < NJ)   pj[x] = Wt + (size_t)(1024 + Stf[bh*40 + j-NTOP])*1024;
      else if (j == NJ)  pj[x] = bias;
      else               pj[x] = Wt;    // j==71: garbage, zeroed in epilogue
    }
    int d = tid & 63, mp = tid >> 6;
    int m0 = (mc << 8) + mp;
    float a0=0.f, a1=0.f, a2=0.f, a3=0.f;
    #pragma unroll 16
    for (int i = 0; i < 64; ++i) {
      int m = m0 + (i << 2);
      float vv = values[(((size_t)(b*1024 + m)*8 + h) << 6) + d];
      a0 = fmaf(pj[0][m], vv, a0);
      a1 = fmaf(pj[1][m], vv, a1);
      a2 = fmaf(pj[2][m], vv, a2);
      a3 = fmaf(pj[3][m], vv, a3);
    }
    float4* red = smbuf;
    red[tid] = make_float4(a0, a1, a2, a3);
    __syncthreads();
    int jj = tid >> 6, dd = tid & 63;
    float4 r0 = red[dd], r1 = red[64+dd], r2 = red[128+dd], r3 = red[192+dd];
    float s;
    if (jj == 0)      s = r0.x + r1.x + r2.x + r3.x;
    else if (jj == 1) s = r0.y + r1.y + r2.y + r3.y;
    else if (jj == 2) s = r0.z + r1.z + r2.z + r3.z;
    else              s = r0.w + r1.w + r2.w + r3.w;
    if (j0 + jj > NJ) s = 0.f;
    WVp[(size_t)mc*73728 + ((size_t)bh*72 + j0 + jj)*64 + dd] = s;
  } else {                              // ---- k4 ----
    int gid = bid - 1152;
    int bh = gid >> 5;  int m0 = (gid & 31) << 5;
    int b = bh >> 3, h = bh & 7;
    float* qs   = f;                    // 35*64
    float* ts   = f + 2240;
    float* sc   = f + 4480;             // 32*73
    float* invs = f + 6816;             // 32
    for (int i = tid; i < NTOP*64; i += 256) {
      int j = i >> 6, e = i & 63;
      qs[i] = q  [(((size_t)(b*1024 + St [bh*40 + j])*8 + h) << 6) + e];
      ts[i] = tfq[(((size_t)(b*1024 + Stf[bh*40 + j])*8 + h) << 6) + e];
    }
    __syncthreads();
    int mi = tid & 31, g = tid >> 5;
    int br = g >> 2, g4 = g & 3;
    int m = m0 + mi;
    const float* src = br ? tfq : k;
    float4 kr[16];
    const float4* p = reinterpret_cast<const float4*>(
        src + (((size_t)(b*1024 + m)*8 + h) << 6));
    #pragma unroll
    for (int i = 0; i < 16; ++i) kr[i] = p[i];
    const float4* fs4 = reinterpret_cast<const float4*>(br ? ts : qs);
    int sb = br ? NTOP : 0;
    for (int j = g4; j < NTOP; j += 4) {
      float s = 0.f;
      #pragma unroll
      for (int e4 = 0; e4 < 16; ++e4) {
        float4 qv = fs4[j*16 + e4];
        s += qv.x*kr[e4].x + qv.y*kr[e4].y + qv.z*kr[e4].z + qv.w*kr[e4].w;
      }
      sc[mi*73 + sb + j] = s * 0.125f;
    }
    __syncthreads();
    if (tid < 32) {
      float mx = -1e30f;
      for (int j = 0; j < NJ; ++j) mx = fmaxf(mx, sc[tid*73 + j]);
      float sum = 0.f;
      for (int j = 0; j < NJ; ++j) {
        float e = __expf(sc[tid*73 + j] - mx);
        sc[tid*73 + j] = e; sum += e;
      }
      invs[tid] = 1.0f / sum;
    }
    __syncthreads();
    float* Pb = P + ((size_t)bh*1024 + m0)*72;
    for (int i = tid; i < 32*72; i += 256) {
      int mm = i / 72, j = i - mm*72;
      Pb[i] = (j < NJ) ? sc[mm*73 + j] * invs[mm] : 0.f;
    }
  }
}

// ---------------- D4: k6 per-bh, 512 thr, LDS Wv + transposed P chunk ----------------
__global__ __launch_bounds__(512) void k6_out(
    const float* __restrict__ P, const float* __restrict__ WVp,
    float* __restrict__ out) {
  __shared__ float wv[72*64];           // 18432 B
  __shared__ float Pl[72*68];           // 19584 B
  int bh = blockIdx.x, lc = blockIdx.y;
  int l0 = lc << 6;
  int b = bh >> 3, h = bh & 7;
  int tid = threadIdx.x;
  {
    const float* W0 = WVp + (size_t)bh*4608;
    for (int i = tid; i < 4608; i += 512)
      wv[i] = W0[i] + W0[73728 + i] + W0[147456 + i] + W0[221184 + i];
  }
  {
    const float* Pg = P + ((size_t)bh*1024 + l0)*72;
    for (int i = tid; i < 4608; i += 512) {
      int l = i / 72, j = i - l*72;
      Pl[j*68 + l] = Pg[i];
    }
  }
  __syncthreads();
  int d = tid & 63, lg = tid >> 6;      // 8 l-groups of 8
  int lb = lg << 3;
  float acc[8];
  float base = wv[NJ*64 + d];
  #pragma unroll
  for (int i = 0; i < 8; ++i) acc[i] = base;
  for (int j = 0; j < NJ; ++j) {
    float wvj = wv[j*64 + d];
    const float4* pr = reinterpret_cast<const float4*>(Pl + j*68 + lb);
    float4 p0 = pr[0], p1 = pr[1];
    acc[0] = fmaf(p0.x, wvj, acc[0]); acc[1] = fmaf(p0.y, wvj, acc[1]);
    acc[2] = fmaf(p0.z, wvj, acc[2]); acc[3] = fmaf(p0.w, wvj, acc[3]);
    acc[4] = fmaf(p1.x, wvj, acc[4]); acc[5] = fmaf(p1.y, wvj, acc[5]);
    acc[6] = fmaf(p1.z, wvj, acc[6]); acc[7] = fmaf(p1.w, wvj, acc[7]);
  }
  #pragma unroll
  for (int i = 0; i < 8; ++i) {
    int l = l0 + lb + i;
    out[(((size_t)(b*1024 + l)*8 + h) << 6) + d] = acc[i];
  }
}

extern "C" void kernel_launch(void* const* d_in, const int* in_sizes, int n_in,
                              void* d_out, int out_size, void* d_ws, size_t ws_size,
                              hipStream_t stream) {
  const float* tfq  = (const float*)d_in[0];
  const float* q    = (const float*)d_in[1];
  const float* k    = (const float*)d_in[2];
  const float* v    = (const float*)d_in[3];
  const float* tw   = (const float*)d_in[5];
  const float* tb   = (const float*)d_in[6];
  float* out = (float*)d_out;

  char* ws = (char*)d_ws;
  float* acp = (float*)(ws);                        // 16,777,216
  int*   St  = (int*)  (ws + 16777216);             // 4 KB
  int*   Stf = (int*)  (ws + 16781312);             // 4 KB
  float* Wt  = (float*)(ws + 16785408);             // 8,388,608
  float* P   = (float*)(ws + 25174016);             // 4,718,592
  float* WVp = (float*)(ws + 29892608);             // 1,179,648

  d1_prep<<<1536, 256, 0, stream>>>(q, k, tw, Wt, acp);
  d2_topk<<<32, 1024, 0, stream>>>(acp, tfq, St, Stf);
  d3_mix <<<1664, 256, 0, stream>>>(q, k, tfq, Wt, tb, v, St, Stf, WVp, P);
  k6_out <<<dim3(16, 16), 512, 0, stream>>>(P, WVp, out);
}